// Round 1
// baseline (918.162 us; speedup 1.0000x reference)
//
#include <hip/hip_runtime.h>

#define NLAT 361
#define NLON 720
#define NF   361            // MMAX = rfft bins = NLON/2+1
#define NCH  32
#define NCK  (NCH * NLAT)   // 11552 rows
#define S1_ROWS 16
#define S2_KC0 184

// twiddle table: tw[j] = e^{-i 2*pi*j/720} = (cos, -sin)
__global__ void k_build_tw(float2* __restrict__ tw) {
    int j = blockIdx.x * blockDim.x + threadIdx.x;
    if (j < NLON) {
        double ang = -2.0 * 3.14159265358979323846 * (double)j / (double)NLON;
        tw[j] = make_float2((float)cos(ang), (float)sin(ang));
    }
}

// Stage 1: xf[f][row] = (2*pi/720) * sum_n x[row][n] e^{-i 2 pi f n / 720}
// row = c*361 + k  (so xf[f] is laid out [c][k] contiguously for stage 2)
__global__ __launch_bounds__(512) void k_stage1(
    const float* __restrict__ x, const float2* __restrict__ twg,
    float* __restrict__ xf_re, float* __restrict__ xf_im) {
    __shared__ float  xs[S1_ROWS][NLON + 1];   // stride 721 (odd mod 32): conflict-free
    __shared__ float2 twl[NLON];
    const int t = threadIdx.x;
    const int ckbase = blockIdx.x * S1_ROWS;

    for (int i = t; i < S1_ROWS * NLON; i += 512) {
        int r = i / NLON, n = i - r * NLON;
        xs[r][n] = x[(ckbase + r) * NLON + n];
    }
    for (int i = t; i < NLON; i += 512) twl[i] = twg[i];
    __syncthreads();

    // in-place fold: xs[n] = x[n]+x[720-n], xs[720-n] = x[n]-x[720-n], n=1..359
    for (int i = t; i < S1_ROWS * 359; i += 512) {
        int r = i / 359, n = 1 + (i - r * 359);
        float a = xs[r][n], b = xs[r][NLON - n];
        xs[r][n]        = a + b;
        xs[r][NLON - n] = a - b;
    }
    __syncthreads();

    const int ck    = t & (S1_ROWS - 1);
    const int fslot = t >> 4;              // 0..31
    const float scale = 6.283185307179586f / (float)NLON;
    for (int fi = 0; fi < 12; ++fi) {
        int f = fi * 32 + fslot;
        if (f < NF) {
            // edge terms n=0 and n=360 (untouched by the fold)
            float ar = xs[ck][0] + ((f & 1) ? -xs[ck][360] : xs[ck][360]);
            float ai = 0.0f;
            int idx = f;                   // idx = (f*n) mod 720 at n=1
            for (int n = 1; n <= 359; ++n) {
                float2 w = twl[idx];
                ar = fmaf(xs[ck][n],        w.x, ar);   // sum (x[n]+x[720-n]) cos
                ai = fmaf(xs[ck][NLON - n], w.y, ai);   // sum (x[n]-x[720-n]) (-sin)
                idx += f;
                if (idx >= NLON) idx -= NLON;
            }
            xf_re[f * NCK + ckbase + ck] = ar * scale;
            xf_im[f * NCK + ckbase + ck] = ai * scale;
        }
    }
}

// Stage 2: out[c,l,m,(re,im)] = sum_k xf[m][c][k] * W[m][l][k]
__global__ __launch_bounds__(512) void k_stage2(
    const float* __restrict__ xf_re, const float* __restrict__ xf_im,
    const float* __restrict__ W, float2* __restrict__ out2) {
    __shared__ float xr[NCH][S2_KC0 + 1];  // stride 185 (odd mod 32): conflict-free
    __shared__ float xi[NCH][S2_KC0 + 1];
    const int m      = blockIdx.x;
    const int lhalf  = blockIdx.y;         // 0 or 1
    const int lbase  = lhalf * 184;
    const int lcount = (lhalf == 0) ? 184 : 177;
    const int t     = threadIdx.x;
    const int c     = t & 31;
    const int lslot = t >> 5;              // 0..15

    float ar[12], ai[12];
    #pragma unroll
    for (int i = 0; i < 12; ++i) { ar[i] = 0.f; ai[i] = 0.f; }

    for (int kc = 0; kc < 2; ++kc) {
        const int k0   = kc * S2_KC0;
        const int klen = (kc == 0) ? 184 : 177;
        __syncthreads();
        for (int i = t; i < NCH * klen; i += 512) {
            int cc = i / klen, kk = i - cc * klen;
            xr[cc][kk] = xf_re[m * NCK + cc * NLAT + k0 + kk];
            xi[cc][kk] = xf_im[m * NCK + cc * NLAT + k0 + kk];
        }
        __syncthreads();
        #pragma unroll
        for (int li = 0; li < 12; ++li) {
            int off = lslot + li * 16;
            if (off >= lcount) continue;
            int l = lbase + off;
            const float* wrow = &W[((size_t)m * NLAT + l) * NLAT + k0];
            float sr = ar[li], si = ai[li];
            for (int k = 0; k < klen; ++k) {
                float w = wrow[k];
                sr = fmaf(xr[c][k], w, sr);
                si = fmaf(xi[c][k], w, si);
            }
            ar[li] = sr; ai[li] = si;
        }
    }

    #pragma unroll
    for (int li = 0; li < 12; ++li) {
        int off = lslot + li * 16;
        if (off >= lcount) continue;
        int l = lbase + off;
        out2[((size_t)c * NLAT + l) * NLAT + m] = make_float2(ar[li], ai[li]);
    }
}

extern "C" void kernel_launch(void* const* d_in, const int* in_sizes, int n_in,
                              void* d_out, int out_size, void* d_ws, size_t ws_size,
                              hipStream_t stream) {
    const float* x = (const float*)d_in[0];
    const float* W = (const float*)d_in[1];
    float2* out2 = (float2*)d_out;

    char* ws = (char*)d_ws;
    float2* tw    = (float2*)ws;                                   // 5,760 B
    float*  xf_re = (float*)(ws + 8192);                           // 16,681,088 B
    float*  xf_im = (float*)(ws + 8192 + (size_t)NF * NCK * 4);    // 16,681,088 B

    k_build_tw<<<3, 256, 0, stream>>>(tw);
    k_stage1<<<NCK / S1_ROWS, 512, 0, stream>>>(x, tw, xf_re, xf_im);
    k_stage2<<<dim3(NF, 2), 512, 0, stream>>>(xf_re, xf_im, W, out2);
}

// Round 2
// 461.450 us; speedup vs baseline: 1.9897x; 1.9897x over previous
//
#include <hip/hip_runtime.h>

#define NLAT 361
#define NLON 720
#define NF   361            // MMAX = rfft bins kept
#define NCH  32
#define NCK  (NCH * NLAT)   // 11552
#define S1_ROWS 16
#define KP   384            // stage2 K padded to 12*32
#define AROW 392            // LDS row stride for A (f16 elems): 784 B = 49 x 16B (odd -> conflict-free)
#define WROW 40             // LDS row stride for W tile (f16 elems): 80 B = 5 x 16B

typedef _Float16 h16;
typedef _Float16 f16x8 __attribute__((ext_vector_type(8)));
typedef float    f32x4 __attribute__((ext_vector_type(4)));

#define PLANE ((size_t)NF * NCH * KP)   // f16 elements per (re|im) plane

// twiddle table: tw[j] = e^{-i 2*pi*j/720} = (cos, -sin)
__global__ void k_build_tw(float2* __restrict__ tw) {
    int j = blockIdx.x * blockDim.x + threadIdx.x;
    if (j < NLON) {
        double ang = -2.0 * 3.14159265358979323846 * (double)j / (double)NLON;
        tw[j] = make_float2((float)cos(ang), (float)sin(ang));
    }
}

// Stage 1: xf[f][c][klat] (f16, K padded to 384) = (2pi/720) * DFT_n x[c,klat,n]
__global__ __launch_bounds__(512) void k_stage1(
    const float* __restrict__ x, const float2* __restrict__ twg,
    h16* __restrict__ xfh) {
    __shared__ float  xs[S1_ROWS][NLON + 1];   // stride 721: conflict-free
    __shared__ float2 twl[NLON];
    const int t = threadIdx.x;
    const int ckbase = blockIdx.x * S1_ROWS;

    for (int i = t; i < S1_ROWS * NLON; i += 512) {
        int r = i / NLON, n = i - r * NLON;
        xs[r][n] = x[(ckbase + r) * NLON + n];
    }
    for (int i = t; i < NLON; i += 512) twl[i] = twg[i];
    __syncthreads();

    // fold: xs[n] = x[n]+x[720-n], xs[720-n] = x[n]-x[720-n], n=1..359
    for (int i = t; i < S1_ROWS * 359; i += 512) {
        int r = i / 359, n = 1 + (i - r * 359);
        float a = xs[r][n], b = xs[r][NLON - n];
        xs[r][n]        = a + b;
        xs[r][NLON - n] = a - b;
    }
    __syncthreads();

    const int ck    = t & (S1_ROWS - 1);
    const int fslot = t >> 4;              // 0..31
    const int row   = ckbase + ck;
    const int c     = row / NLAT;
    const int klat  = row - c * NLAT;
    const float scale = 6.283185307179586f / (float)NLON;
    for (int fi = 0; fi < 12; ++fi) {
        int f = fi * 32 + fslot;
        if (f < NF) {
            float ar = xs[ck][0] + ((f & 1) ? -xs[ck][360] : xs[ck][360]);
            float ai = 0.0f;
            int idx = f;
            for (int n = 1; n <= 359; ++n) {
                float2 w = twl[idx];
                ar = fmaf(xs[ck][n],        w.x, ar);
                ai = fmaf(xs[ck][NLON - n], w.y, ai);
                idx += f;
                if (idx >= NLON) idx -= NLON;
            }
            size_t a = ((size_t)(f * NCH + c)) * KP + klat;
            xfh[a]         = (h16)(ar * scale);
            xfh[PLANE + a] = (h16)(ai * scale);
        }
    }
}

// Stage 2 (MFMA): outws[m][c][l] = sum_k xf[m][c][k] * W[m][l][k]  (re,im)
__global__ __launch_bounds__(256) void k_stage2(
    const h16* __restrict__ xfh, const float* __restrict__ W,
    float2* __restrict__ outws) {
    __shared__ h16 Ah[2 * NCH * AROW];   // 50,176 B
    __shared__ h16 Wh[192 * WROW];       // 15,360 B
    const int m     = blockIdx.x;
    const int lhalf = blockIdx.y;
    const int l0    = lhalf * 184;
    const int lcount= lhalf ? 177 : 184;
    const int t     = threadIdx.x;
    const int lane  = t & 63;
    const int wv    = t >> 6;            // wave 0..3
    const int col   = lane & 15;
    const int krow  = lane >> 4;         // 0..3

    // stage A (once): 2 planes x 32 c x 48 16B-chunks = 3072 tasks
    #pragma unroll
    for (int i = 0; i < 12; ++i) {
        int task = t + i * 256;
        int ri   = task / 1536;
        int rem  = task - ri * 1536;
        int c    = rem / 48, k8 = rem - c * 48;
        f16x8 v = *(const f16x8*)&xfh[(size_t)ri * PLANE + ((size_t)(m * NCH + c)) * KP + k8 * 8];
        *(f16x8*)&Ah[(ri * NCH + c) * AROW + k8 * 8] = v;
    }

    f32x4 acc[3][2][2];
    #pragma unroll
    for (int li = 0; li < 3; ++li)
        #pragma unroll
        for (int ct = 0; ct < 2; ++ct)
            #pragma unroll
            for (int ri = 0; ri < 2; ++ri)
                acc[li][ct][ri] = (f32x4)0.0f;

    for (int ks = 0; ks < 12; ++ks) {
        __syncthreads();   // waves done reading Wh (and A staged on first iter)
        // stage W tile: 192 rows x 32 k, coalesced dword loads (lanes sweep k)
        #pragma unroll
        for (int i = 0; i < 24; ++i) {
            int idx = t + i * 256;
            int row = idx >> 5, kk = idx & 31;
            int k   = ks * 32 + kk;
            float v = 0.0f;
            if (row < lcount && k < NLAT)
                v = W[((size_t)m * NLAT + l0 + row) * NLAT + k];
            Wh[row * WROW + kk] = (h16)v;
        }
        __syncthreads();

        f16x8 af[2][2];
        #pragma unroll
        for (int ct = 0; ct < 2; ++ct)
            #pragma unroll
            for (int ri = 0; ri < 2; ++ri)
                af[ct][ri] = *(const f16x8*)&Ah[(ri * NCH + ct * 16 + col) * AROW + ks * 32 + krow * 8];

        #pragma unroll
        for (int li = 0; li < 3; ++li) {
            int lt = wv + li * 4;
            f16x8 bf = *(const f16x8*)&Wh[(lt * 16 + col) * WROW + krow * 8];
            #pragma unroll
            for (int ct = 0; ct < 2; ++ct)
                #pragma unroll
                for (int ri = 0; ri < 2; ++ri)
                    acc[li][ct][ri] = __builtin_amdgcn_mfma_f32_16x16x32_f16(
                        af[ct][ri], bf, acc[li][ct][ri], 0, 0, 0);
        }
    }

    // epilogue: D layout col(l)=lane&15, row(c)=(lane>>4)*4+reg
    #pragma unroll
    for (int li = 0; li < 3; ++li) {
        int lt = wv + li * 4;
        int l  = lt * 16 + col;
        if (l < lcount) {
            #pragma unroll
            for (int ct = 0; ct < 2; ++ct) {
                #pragma unroll
                for (int r = 0; r < 4; ++r) {
                    int c = ct * 16 + krow * 4 + r;
                    outws[((size_t)m * NCH + c) * NLAT + (l0 + l)] =
                        make_float2(acc[li][ct][0][r], acc[li][ct][1][r]);
                }
            }
        }
    }
}

// Transpose: out[cl][m] = ws[m][cl]   (float2 elements), 361 x 11552
__global__ __launch_bounds__(256) void k_transpose(
    const float2* __restrict__ src, float2* __restrict__ dst) {
    __shared__ float2 tile[32][33];
    const int tx = threadIdx.x & 31, ty = threadIdx.x >> 5;
    const int cl0 = blockIdx.x * 32, m0 = blockIdx.y * 32;
    #pragma unroll
    for (int i = 0; i < 4; ++i) {
        int mm = m0 + ty + i * 8;
        if (mm < NLAT) tile[ty + i * 8][tx] = src[(size_t)mm * NCK + cl0 + tx];
    }
    __syncthreads();
    #pragma unroll
    for (int i = 0; i < 4; ++i) {
        int mm = m0 + tx;
        int cl = cl0 + ty + i * 8;
        if (mm < NLAT) dst[(size_t)cl * NLAT + mm] = tile[tx][ty + i * 8];
    }
}

extern "C" void kernel_launch(void* const* d_in, const int* in_sizes, int n_in,
                              void* d_out, int out_size, void* d_ws, size_t ws_size,
                              hipStream_t stream) {
    const float* x = (const float*)d_in[0];
    const float* W = (const float*)d_in[1];
    float2* out2 = (float2*)d_out;

    char* ws = (char*)d_ws;
    float2* tw    = (float2*)ws;                         // 5,760 B (pad to 8192)
    h16*    xfh   = (h16*)(ws + 8192);                   // 2 planes: 17,743,872 B
    float2* outws = (float2*)(ws + 8192 + 2 * PLANE * sizeof(h16)); // 33,362,176 B

    k_build_tw<<<3, 256, 0, stream>>>(tw);
    hipMemsetAsync(xfh, 0, 2 * PLANE * sizeof(h16), stream);  // zero K-pad
    k_stage1<<<NCK / S1_ROWS, 512, 0, stream>>>(x, tw, xfh);
    k_stage2<<<dim3(NF, 2), 256, 0, stream>>>(xfh, W, outws);
    k_transpose<<<dim3(361, 12), 256, 0, stream>>>(outws, out2);
}

// Round 3
// 174.748 us; speedup vs baseline: 5.2542x; 2.6407x over previous
//
#include <hip/hip_runtime.h>

#define NLAT 361
#define NLON 720
#define NF   361            // MMAX = rfft bins kept
#define NCH  32
#define NCK  (NCH * NLAT)   // 11552
#define KP   384            // stage2 K padded (per channel)
#define KD   768            // stage1 DFT K padded (n samples)
#define MD   384            // stage1 DFT M padded (f)
#define AROW 392            // stage2 LDS row stride for A
#define WROW 40             // stage2 LDS row stride for W tile
#define BROW 72             // stage1 LDS row stride (f16): 144B, 2-way max aliasing

typedef _Float16 h16;
typedef _Float16 f16x4 __attribute__((ext_vector_type(4)));
typedef _Float16 f16x8 __attribute__((ext_vector_type(8)));
typedef float    f32x4 __attribute__((ext_vector_type(4)));

#define PLANE ((size_t)NF * NCH * KP)   // f16 elements per (re|im) plane

// twiddle table: tw[j] = e^{-i 2*pi*j/720} = (cos, -sin)
__global__ void k_build_tw(float2* __restrict__ tw) {
    int j = blockIdx.x * blockDim.x + threadIdx.x;
    if (j < NLON) {
        double ang = -2.0 * 3.14159265358979323846 * (double)j / (double)NLON;
        tw[j] = make_float2((float)cos(ang), (float)sin(ang));
    }
}

// Expand twiddles into padded f16 DFT matrices, scale folded in.
__global__ __launch_bounds__(256) void k_build_T(
    const float2* __restrict__ tw, h16* __restrict__ Tre, h16* __restrict__ Tim) {
    int idx = blockIdx.x * 256 + threadIdx.x;
    if (idx >= MD * KD) return;
    int f = idx / KD, n = idx - f * KD;
    float re = 0.f, im = 0.f;
    if (f < NF && n < NLON) {
        float2 w = tw[(f * n) % NLON];
        const float scale = 6.283185307179586f / (float)NLON;
        re = w.x * scale; im = w.y * scale;
    }
    Tre[idx] = (h16)re;
    Tim[idx] = (h16)im;
}

// Stage 1 (MFMA): xf[pl][f][c][klat] = sum_n T[pl][f][n] * x[c,klat][n]
__global__ __launch_bounds__(256) void k_stage1m(
    const float* __restrict__ x, const h16* __restrict__ Tre,
    const h16* __restrict__ Tim, h16* __restrict__ xfh) {
    __shared__ h16 As[2][64][BROW];   // 18,432 B
    __shared__ h16 Bs[64][BROW];      //  9,216 B
    const int t    = threadIdx.x;
    const int f0   = blockIdx.x * 64;   // 0..320
    const int n0   = blockIdx.y * 64;   // 0..11520
    const int lane = t & 63, wv = t >> 6;
    const int wm   = wv & 1, wn = wv >> 1;   // wave tile 32(f) x 32(row)
    const int col  = lane & 15, kq = lane >> 4;

    f32x4 acc[2][2][2];  // [plane][mt][nt]
    #pragma unroll
    for (int p = 0; p < 2; ++p)
        #pragma unroll
        for (int a = 0; a < 2; ++a)
            #pragma unroll
            for (int b = 0; b < 2; ++b) acc[p][a][b] = (f32x4)0.0f;

    for (int ks = 0; ks < 12; ++ks) {
        __syncthreads();
        // stage A: 2 planes x 64 f-rows x 8 chunks(8 f16) = 1024 tasks
        #pragma unroll
        for (int i = 0; i < 4; ++i) {
            int task = t + i * 256;
            int pl   = task >> 9;
            int rem  = task & 511;
            int r    = rem >> 3, ch = rem & 7;
            const h16* Tp = pl ? Tim : Tre;
            f16x8 v = *(const f16x8*)&Tp[(size_t)(f0 + r) * KD + ks * 64 + ch * 8];
            *(f16x8*)&As[pl][r][ch * 8] = v;
        }
        // stage B: x tile 64 rows x 64 n (f32 -> f16)
        #pragma unroll
        for (int p = 0; p < 4; ++p) {
            int r = p * 16 + (t >> 4), c4 = t & 15;
            int rowg = n0 + r;
            int n = ks * 64 + c4 * 4;
            float4 v = make_float4(0.f, 0.f, 0.f, 0.f);
            if (rowg < NCK && n < NLON)
                v = *(const float4*)&x[(size_t)rowg * NLON + n];
            f16x4 h = { (h16)v.x, (h16)v.y, (h16)v.z, (h16)v.w };
            *(f16x4*)&Bs[r][c4 * 4] = h;
        }
        __syncthreads();
        #pragma unroll
        for (int kk = 0; kk < 2; ++kk) {
            f16x8 bfr[2], afr[2][2];
            #pragma unroll
            for (int nt = 0; nt < 2; ++nt)
                bfr[nt] = *(const f16x8*)&Bs[wn * 32 + nt * 16 + col][kk * 32 + kq * 8];
            #pragma unroll
            for (int pl = 0; pl < 2; ++pl)
                #pragma unroll
                for (int mt = 0; mt < 2; ++mt)
                    afr[pl][mt] = *(const f16x8*)&As[pl][wm * 32 + mt * 16 + col][kk * 32 + kq * 8];
            #pragma unroll
            for (int pl = 0; pl < 2; ++pl)
                #pragma unroll
                for (int mt = 0; mt < 2; ++mt)
                    #pragma unroll
                    for (int nt = 0; nt < 2; ++nt)
                        acc[pl][mt][nt] = __builtin_amdgcn_mfma_f32_16x16x32_f16(
                            afr[pl][mt], bfr[nt], acc[pl][mt][nt], 0, 0, 0);
        }
    }

    // epilogue: D row = f (kq*4+reg), D col = rowg (col)
    #pragma unroll
    for (int nt = 0; nt < 2; ++nt) {
        int rowg = n0 + wn * 32 + nt * 16 + col;
        if (rowg >= NCK) continue;
        int c    = rowg / NLAT;
        int klat = rowg - c * NLAT;
        size_t cbase = (size_t)c * KP + klat;
        #pragma unroll
        for (int pl = 0; pl < 2; ++pl)
            #pragma unroll
            for (int mt = 0; mt < 2; ++mt)
                #pragma unroll
                for (int r = 0; r < 4; ++r) {
                    int f = f0 + wm * 32 + mt * 16 + kq * 4 + r;
                    if (f < NF)
                        xfh[(size_t)pl * PLANE + (size_t)f * NCH * KP + cbase] =
                            (h16)acc[pl][mt][nt][r];
                }
    }
}

// Stage 2 (MFMA): outws[m][c][l] = sum_k xf[m][c][k] * W[m][l][k]  (re,im)
__global__ __launch_bounds__(256) void k_stage2(
    const h16* __restrict__ xfh, const float* __restrict__ W,
    float2* __restrict__ outws) {
    __shared__ h16 Ah[2 * NCH * AROW];   // 50,176 B
    __shared__ h16 Wh[192 * WROW];       // 15,360 B
    const int m     = blockIdx.x;
    const int lhalf = blockIdx.y;
    const int l0    = lhalf * 184;
    const int lcount= lhalf ? 177 : 184;
    const int t     = threadIdx.x;
    const int lane  = t & 63;
    const int wv    = t >> 6;
    const int col   = lane & 15;
    const int krow  = lane >> 4;

    #pragma unroll
    for (int i = 0; i < 12; ++i) {
        int task = t + i * 256;
        int ri   = task / 1536;
        int rem  = task - ri * 1536;
        int c    = rem / 48, k8 = rem - c * 48;
        f16x8 v = *(const f16x8*)&xfh[(size_t)ri * PLANE + ((size_t)(m * NCH + c)) * KP + k8 * 8];
        *(f16x8*)&Ah[(ri * NCH + c) * AROW + k8 * 8] = v;
    }

    f32x4 acc[3][2][2];
    #pragma unroll
    for (int li = 0; li < 3; ++li)
        #pragma unroll
        for (int ct = 0; ct < 2; ++ct)
            #pragma unroll
            for (int ri = 0; ri < 2; ++ri)
                acc[li][ct][ri] = (f32x4)0.0f;

    for (int ks = 0; ks < 12; ++ks) {
        __syncthreads();
        #pragma unroll
        for (int i = 0; i < 24; ++i) {
            int idx = t + i * 256;
            int row = idx >> 5, kk = idx & 31;
            int k   = ks * 32 + kk;
            float v = 0.0f;
            if (row < lcount && k < NLAT)
                v = W[((size_t)m * NLAT + l0 + row) * NLAT + k];
            Wh[row * WROW + kk] = (h16)v;
        }
        __syncthreads();

        f16x8 af[2][2];
        #pragma unroll
        for (int ct = 0; ct < 2; ++ct)
            #pragma unroll
            for (int ri = 0; ri < 2; ++ri)
                af[ct][ri] = *(const f16x8*)&Ah[(ri * NCH + ct * 16 + col) * AROW + ks * 32 + krow * 8];

        #pragma unroll
        for (int li = 0; li < 3; ++li) {
            int lt = wv + li * 4;
            f16x8 bf = *(const f16x8*)&Wh[(lt * 16 + col) * WROW + krow * 8];
            #pragma unroll
            for (int ct = 0; ct < 2; ++ct)
                #pragma unroll
                for (int ri = 0; ri < 2; ++ri)
                    acc[li][ct][ri] = __builtin_amdgcn_mfma_f32_16x16x32_f16(
                        af[ct][ri], bf, acc[li][ct][ri], 0, 0, 0);
        }
    }

    #pragma unroll
    for (int li = 0; li < 3; ++li) {
        int lt = wv + li * 4;
        int l  = lt * 16 + col;
        if (l < lcount) {
            #pragma unroll
            for (int ct = 0; ct < 2; ++ct) {
                #pragma unroll
                for (int r = 0; r < 4; ++r) {
                    int c = ct * 16 + krow * 4 + r;
                    outws[((size_t)m * NCH + c) * NLAT + (l0 + l)] =
                        make_float2(acc[li][ct][0][r], acc[li][ct][1][r]);
                }
            }
        }
    }
}

// Transpose: out[cl][m] = ws[m][cl]   (float2 elements), 361 x 11552
__global__ __launch_bounds__(256) void k_transpose(
    const float2* __restrict__ src, float2* __restrict__ dst) {
    __shared__ float2 tile[32][33];
    const int tx = threadIdx.x & 31, ty = threadIdx.x >> 5;
    const int cl0 = blockIdx.x * 32, m0 = blockIdx.y * 32;
    #pragma unroll
    for (int i = 0; i < 4; ++i) {
        int mm = m0 + ty + i * 8;
        if (mm < NLAT) tile[ty + i * 8][tx] = src[(size_t)mm * NCK + cl0 + tx];
    }
    __syncthreads();
    #pragma unroll
    for (int i = 0; i < 4; ++i) {
        int mm = m0 + tx;
        int cl = cl0 + ty + i * 8;
        if (mm < NLAT) dst[(size_t)cl * NLAT + mm] = tile[tx][ty + i * 8];
    }
}

extern "C" void kernel_launch(void* const* d_in, const int* in_sizes, int n_in,
                              void* d_out, int out_size, void* d_ws, size_t ws_size,
                              hipStream_t stream) {
    const float* x = (const float*)d_in[0];
    const float* W = (const float*)d_in[1];
    float2* out2 = (float2*)d_out;

    char* ws = (char*)d_ws;
    float2* tw    = (float2*)ws;                              // 5,760 B (pad 8192)
    h16*    Tre   = (h16*)(ws + 8192);                        // 589,824 B
    h16*    Tim   = (h16*)(ws + 8192 + 589824);               // 589,824 B
    h16*    xfh   = (h16*)(ws + 1187840);                     // 17,743,872 B
    float2* outws = (float2*)(ws + 1187840 + 2 * PLANE * sizeof(h16));

    k_build_tw<<<3, 256, 0, stream>>>(tw);
    k_build_T<<<(MD * KD + 255) / 256, 256, 0, stream>>>(tw, Tre, Tim);
    hipMemsetAsync(xfh, 0, 2 * PLANE * sizeof(h16), stream);  // zero klat pads
    k_stage1m<<<dim3(6, 181), 256, 0, stream>>>(x, Tre, Tim, xfh);
    k_stage2<<<dim3(NF, 2), 256, 0, stream>>>(xfh, W, outws);
    k_transpose<<<dim3(361, 12), 256, 0, stream>>>(outws, out2);
}